// Round 9
// baseline (1211.283 us; speedup 1.0000x reference)
//
#include <hip/hip_runtime.h>

// MFMA-based fully-fused 5-layer bidirectional GRU -- max-occupancy version.
//
// r8 analysis: 353 VALU-issue-cy/wave-step (18 quarter-rate trans ops
// dominate) -> VALU-issue floor ~319us; r8 ran 419us at 76% VALUBusy with
// 4 waves/SIMD (19.4KB LDS -> 8 blocks/CU). This round: LDS -> 0 (the seq
// buffer moves to a second global ping-pong buffer; ds_bpermute needs no LDS
// allocation) -> 16 blocks/CU = 8 waves/SIMD = 32 waves/CU cap. Active set
// 4096 resident blocks x 38.4KB = 157MB < 256MB L3 -> Infinity-Cache
// resident; HBM sees eviction writebacks only. Same-CU store->barrier->load
// coherence proven r7/r8 (__syncthreads drains vmcnt).
//
// Dataflow: L0: x->G0; L1: G0->G1; L2: G1->G0; L3: G0->G1; L4: G1->out
// (bwd needs only its first step). Global reads prefetched 2 steps ahead.
//
// Per step, ONE v_mfma_f32_32x32x16_f16 computes every gate pre-activation
// for 32 batch elems of one direction (wave0 = fwd, wave1 = bwd):
//   A (32x16 const): row r = 8q+4h+g holds unit u=2q+1-h, gate g in
//     {r,z,i_n,h_n}; k0..9 = W_ih (10 input ch), k10..14 = W_hh. i_n/h_n in
//     separate rows so n = tanh(i_n + r*h_n) stays exact; exp2 scales folded.
//   B (16x32 per step): col = batch; k0..9 = prev-layer output, k10..14 =
//     own h (register recurrence).  C = bias fragment (re-added free).
// D layout (row=(reg&3)+8*(reg>>2)+4*half): lane quad q = unit 2q+1-half ->
// half1 owns u{0,2,4}, needs only u{1,3} from half0: ONE ds_bpermute + 2
// v_perm per step (verified r2/r6; permlane32_swap failed r3/r4 -> banned).
//
// Sequences: f16 pair-planes seq[t][unit][batch], fwd lo / bwd hi halfword.

#define NB 262144
#define T 30
#define NBLK (NB / 32)
#define SEQW (T * 5 * 32)          // u32 per per-block sequence buffer

typedef _Float16 f16x8 __attribute__((ext_vector_type(8)));
typedef float f32x16 __attribute__((ext_vector_type(16)));

__device__ unsigned g_seq[(unsigned long long)NBLK * 2 * SEQW];   // 315 MB

#define SIG_SCALE  (-1.4426950408889634f)   // -log2(e)
#define TANH_SCALE ( 2.8853900817779268f)   // 2*log2(e)

__device__ __forceinline__ float sig_s(float xs) {
    return __builtin_amdgcn_rcpf(1.0f + __builtin_amdgcn_exp2f(xs));
}
__device__ __forceinline__ float tanh_s(float xs) {
    return fmaf(-2.0f, __builtin_amdgcn_rcpf(1.0f + __builtin_amdgcn_exp2f(xs)), 1.0f);
}
__device__ __forceinline__ unsigned packh(_Float16 a, _Float16 b) {
    union { _Float16 f; unsigned short s; } ua, ub;
    ua.f = a; ub.f = b;
    return (unsigned)ua.s | ((unsigned)ub.s << 16);
}

// One direction of one layer. seqR/seqW: [T][5][32] u32 pair-plane buffers
// in global memory; xg: per-block x base (layer 0 only).
template <bool IS_L0, int NT, bool WRITE, bool STORE>
__device__ __forceinline__ void run_layer(
    const float* __restrict__ wih, const float* __restrict__ whh,
    const float* __restrict__ bih, const float* __restrict__ bhh,
    const unsigned* seqR, unsigned* seqW, const float* xg,
    float* outp, const int d, const int lane)
{
    const int lr   = lane & 31;    // A row / B,D column (batch)
    const int half = lane >> 5;    // k-half for A/B; D-row half bit

    // ---- A fragment: row lr = 8q+4h+g -> unit u_r = 2q+1-h, gate g ----
    const int q_r = lr >> 3;
    const int h_r = (lr >> 2) & 1;
    const int g   = lr & 3;        // 0=r 1=z 2=i_n 3=h_n
    const int u_r = 2 * q_r + 1 - h_r;
    const bool rv = (q_r < 3) && (u_r < 5);   // rows 16-19 & 24-31 zero

    f16x8 af;
#pragma unroll
    for (int e = 0; e < 8; e++) {
        const int k = 8 * half + e;           // elem e <-> k = 8*half + e
        float v = 0.f;
        if (rv) {
            if (!IS_L0) {
                if (k < 10) {                       // input channels
                    const int j = (k & 1) * 5 + (k >> 1);   // concat col
                    if (g == 0)      v = SIG_SCALE  * wih[u_r * 10 + j];
                    else if (g == 1) v = SIG_SCALE  * wih[(5 + u_r) * 10 + j];
                    else if (g == 2) v = TANH_SCALE * wih[(10 + u_r) * 10 + j];
                } else if (k < 15) {                // own-dir hidden
                    const int uh = k - 10;
                    if (g == 0)      v = SIG_SCALE  * whh[u_r * 5 + uh];
                    else if (g == 1) v = SIG_SCALE  * whh[(5 + u_r) * 5 + uh];
                    else if (g == 3) v = TANH_SCALE * whh[(10 + u_r) * 5 + uh];
                }
            } else {
                if (k == 0) {                       // input dim 1
                    if (g == 0)      v = SIG_SCALE  * wih[u_r];
                    else if (g == 1) v = SIG_SCALE  * wih[5 + u_r];
                    else if (g == 2) v = TANH_SCALE * wih[10 + u_r];
                } else if (k >= 10 && k < 15) {
                    const int uh = k - 10;
                    if (g == 0)      v = SIG_SCALE  * whh[u_r * 5 + uh];
                    else if (g == 1) v = SIG_SCALE  * whh[(5 + u_r) * 5 + uh];
                    else if (g == 3) v = TANH_SCALE * whh[(10 + u_r) * 5 + uh];
                }
            }
        }
        af[e] = (_Float16)v;
    }

    // ---- bias fragment (C): quad q -> unit u = 2q+1-half ----
    f32x16 bc;
#pragma unroll
    for (int q = 0; q < 4; q++) {
        const int u = 2 * q + 1 - half;
        float b0 = 0.f, b1 = 0.f, b2 = 0.f, b3 = 0.f;
        if (q < 3 && u < 5) {
            b0 = SIG_SCALE  * (bih[u] + bhh[u]);
            b1 = SIG_SCALE  * (bih[5 + u] + bhh[5 + u]);
            b2 = TANH_SCALE * bih[10 + u];
            b3 = TANH_SCALE * bhh[10 + u];
        }
        bc[4 * q + 0] = b0; bc[4 * q + 1] = b1;
        bc[4 * q + 2] = b2; bc[4 * q + 3] = b3;
    }

    // ---- step state ----
    const int sdir = d ? -1 : 1;
    const int p0   = d ? (T - 1) : 0;
    const unsigned* rbase = seqR + p0 * 160 + lr;
    const int r0off = half ? 128 : 0;            // half1 reads plane4 (ch8,9)
    _Float16* wbase = (_Float16*)seqW + p0 * 320 + lr * 2 + d;
    const int rstep = sdir * 160, wstep = sdir * 320;
    const int paddr = (lane ^ 32) << 2;          // cross-half partner

    // h0 = unit (1-half), h1 = unit (3-half), h2 = unit 4 (half1 only)
    float h0 = 0.f, h1 = 0.f, h2 = 0.f;
    unsigned pb1 = 0, pb2 = 0, pb3 = 0;          // h-slots of B (k10..15)

    auto step = [&](unsigned B0, unsigned B1, unsigned B2, unsigned B3) {
        union { f16x8 v; unsigned u[4]; } B;
        B.u[0] = B0;
        B.u[1] = half ? pb1 : B1;
        B.u[2] = half ? pb2 : B2;
        B.u[3] = half ? pb3 : B3;

        const f32x16 D = __builtin_amdgcn_mfma_f32_32x32x16_f16(af, B.v, bc, 0, 0, 0);

        float r, z, n;
        r = sig_s(D[0]); z = sig_s(D[1]);
        n = tanh_s(fmaf(r, D[3], D[2]));
        h0 = fmaf(z, h0 - n, n);
        r = sig_s(D[4]); z = sig_s(D[5]);
        n = tanh_s(fmaf(r, D[7], D[6]));
        h1 = fmaf(z, h1 - n, n);

        // single cross-half exchange, issued early; hides under u4 chain
        const _Float16 q0f = (_Float16)h0, q1f = (_Float16)h1;
        const unsigned pks = packh(q0f, q1f);
        const unsigned o = (unsigned)__builtin_amdgcn_ds_bpermute(paddr, (int)pks);

        r = sig_s(D[8]); z = sig_s(D[9]);
        n = tanh_s(fmaf(r, D[11], D[10]));
        h2 = fmaf(z, h2 - n, n);                 // zero-rows on half0: harmless
        const _Float16 q2f = (_Float16)h2;

        pb1 = __builtin_amdgcn_perm(pks, o, 0x01000504u);  // [h_u0, h_u1]
        pb2 = __builtin_amdgcn_perm(pks, o, 0x03020706u);  // [h_u2, h_u3]
        pb3 = packh(q2f, (_Float16)0.f);                   // [h_u4, 0]

        if constexpr (WRITE) {
            wbase[(1 - half) * 64] = q0f;
            wbase[(3 - half) * 64] = q1f;
            if (half) wbase[4 * 64] = q2f;
            wbase += wstep;
        }
    };

    if constexpr (IS_L0) {
        // x direct from global, 1-step prefetch; lines cache-resident
        const float* xp = xg + lr * T + p0;
        float xf = *xp;
        for (int s = 0; s < NT; s++) {
            const unsigned xv = packh((_Float16)xf, (_Float16)0.f);
            if (s + 1 < NT) { xp += sdir; xf = *xp; }
            step(half ? 0u : xv, 0u, 0u, 0u);
        }
    } else if constexpr (NT == 1) {
        // layer-4 bwd: single step
        const unsigned a0 = rbase[r0off], a1 = rbase[32],
                       a2 = rbase[64],   a3 = rbase[96];
        step(a0, a1, a2, a3);
    } else {
        // global reads: two reg sets, prefetch 2 positions ahead (vmcnt)
        const unsigned* rn = rbase;
        unsigned a0 = rn[r0off], a1 = rn[32], a2 = rn[64], a3 = rn[96];
        rn += rstep;
        unsigned b0 = rn[r0off], b1 = rn[32], b2 = rn[64], b3 = rn[96];
        rn += rstep;
        for (int s = 0; s < NT; s += 2) {
            step(a0, a1, a2, a3);
            if (s + 2 < NT) {
                a0 = rn[r0off]; a1 = rn[32]; a2 = rn[64]; a3 = rn[96];
                rn += rstep;
            }
            step(b0, b1, b2, b3);
            if (s + 3 < NT) {
                b0 = rn[r0off]; b1 = rn[32]; b2 = rn[64]; b3 = rn[96];
                rn += rstep;
            }
        }
    }

    if constexpr (STORE) {               // ys[T-1] for this direction
        outp[1 - half] = h0;
        outp[3 - half] = h1;
        if (half) outp[4] = h2;
    }
}

__global__ void __launch_bounds__(128, 8) gru_all(
    const float* __restrict__ x,
    const float* __restrict__ wih0, const float* __restrict__ whh0,
    const float* __restrict__ bih0, const float* __restrict__ bhh0,
    const float* __restrict__ wihL, const float* __restrict__ whhL,
    const float* __restrict__ bihL, const float* __restrict__ bhhL,
    float* __restrict__ out)
{
    const int tid  = threadIdx.x;
    const int d    = tid >> 6;                   // wave0 = fwd, wave1 = bwd
    const int lane = tid & 63;
    const int lr   = lane & 31;
    const long base = (long)blockIdx.x * 32;

    const float* xg = x + base * T;
    unsigned* G0 = g_seq + (unsigned long long)blockIdx.x * (2 * SEQW);
    unsigned* G1 = G0 + SEQW;

    // L0: x -> G0
    run_layer<true, T, true, false>(
        wih0 + d * 15, whh0 + d * 75, bih0 + d * 15, bhh0 + d * 15,
        nullptr, G0, xg, nullptr, d, lane);
    __syncthreads();

    // L1: G0 -> G1
    run_layer<false, T, true, false>(
        wihL + (0 + d) * 150, whhL + (0 + d) * 75, bihL + (0 + d) * 15, bhhL + (0 + d) * 15,
        G0, G1, nullptr, nullptr, d, lane);
    __syncthreads();

    // L2: G1 -> G0
    run_layer<false, T, true, false>(
        wihL + (2 + d) * 150, whhL + (2 + d) * 75, bihL + (2 + d) * 15, bhhL + (2 + d) * 15,
        G1, G0, nullptr, nullptr, d, lane);
    __syncthreads();

    // L3: G0 -> G1
    run_layer<false, T, true, false>(
        wihL + (4 + d) * 150, whhL + (4 + d) * 75, bihL + (4 + d) * 15, bhhL + (4 + d) * 15,
        G0, G1, nullptr, nullptr, d, lane);
    __syncthreads();

    // L4: G1 -> out; fwd runs 30 steps, bwd needs only its first step
    {
        float* op = out + (base + lr) * 10 + d * 5;
        if (d == 0)
            run_layer<false, T, false, true>(
                wihL + 6 * 150, whhL + 6 * 75, bihL + 6 * 15, bhhL + 6 * 15,
                G1, nullptr, nullptr, op, d, lane);
        else
            run_layer<false, 1, false, true>(
                wihL + 7 * 150, whhL + 7 * 75, bihL + 7 * 15, bhhL + 7 * 15,
                G1, nullptr, nullptr, op, d, lane);
    }
}

extern "C" void kernel_launch(void* const* d_in, const int* in_sizes, int n_in,
                              void* d_out, int out_size, void* d_ws, size_t ws_size,
                              hipStream_t stream) {
    const float* x    = (const float*)d_in[0];
    const float* wih0 = (const float*)d_in[1];
    const float* whh0 = (const float*)d_in[2];
    const float* bih0 = (const float*)d_in[3];
    const float* bhh0 = (const float*)d_in[4];
    const float* wihL = (const float*)d_in[5];
    const float* whhL = (const float*)d_in[6];
    const float* bihL = (const float*)d_in[7];
    const float* bhhL = (const float*)d_in[8];
    float* out = (float*)d_out;

    gru_all<<<NBLK, 128, 0, stream>>>(x, wih0, whh0, bih0, bhh0,
                                      wihL, whhL, bihL, bhhL, out);
}

// Round 10
// 453.445 us; speedup vs baseline: 2.6713x; 2.6713x over previous
//
#include <hip/hip_runtime.h>

// MFMA-based fully-fused 5-layer bidirectional GRU -- r8 structure + reduced
// transcendental count.
//
// r9 lesson (hardware): Infinity Cache does NOT absorb a 157MB ping-pong set;
// per-XCD footprint must fit the 4MB L2 (r9: 19.7MB/XCD -> 2.87GB HBM traffic,
// VALUBusy 27%). r8's config (one 19.2KB LDS buffer + one 19.2KB global
// buffer, 8 blocks/CU -> 4.9MB/XCD) is the constrained optimum of
// occupancy x L2-capacity; plane-split hybrids at 10+ blocks/CU all exceed L2.
//
// This round keeps r8 exactly and attacks the VALU-issue floor (~355cy/step,
// ~290cy = 18 quarter-rate trans ops): shared-reciprocal activations.
//   per unit: rp = rcp((1+Er)(1+Ez)); r = rp*(1+Ez); z = rp*(1+Er)  (2 rcp->1)
//   u0/u1 tanh pair-share one rcp; u2 tanh stays single and sits AFTER the
//   ds_bpermute issue so the exchange latency remains hidden (r8 chain shape).
// 9 rcp -> 5; 18 -> 14 trans/step (-64cy) at +12 mul (+24cy) ~= -40cy/step.
// Pure algebraic transform; rcp-path error ~1e-7 << f16 storage rounding.
//
// Structure (verified r8): block = 2 waves (wave0 fwd, wave1 bwd), 32 batch.
// Dataflow: L0: x->S(LDS); L1: S->G; L2: G->S; L3: S->G; L4: G->out (bwd
// needs only its first step). Global reads prefetched 2 steps ahead.
//
// Per step, ONE v_mfma_f32_32x32x16_f16 computes every gate pre-activation
// for 32 batch elems of one direction:
//   A (32x16 const): row r = 8q+4h+g holds unit u=2q+1-h, gate g in
//     {r,z,i_n,h_n}; k0..9 = W_ih (10 input ch), k10..14 = W_hh. i_n/h_n in
//     separate rows so n = tanh(i_n + r*h_n) stays exact; exp2 scales folded.
//   B (16x32 per step): col = batch; k0..9 = prev-layer output, k10..14 =
//     own h (register recurrence).  C = bias fragment (re-added free).
// D layout (row=(reg&3)+8*(reg>>2)+4*half): lane quad q = unit 2q+1-half ->
// half1 owns u{0,2,4}, needs only u{1,3} from half0: ONE ds_bpermute + 2
// v_perm per step (verified r2/r6; permlane32_swap failed r3/r4 -> banned).
//
// Sequences: f16 pair-planes seq[t][unit][batch], fwd lo / bwd hi halfword.

#define NB 262144
#define T 30
#define NBLK (NB / 32)
#define SEQW (T * 5 * 32)          // u32 per per-block sequence buffer

typedef _Float16 f16x8 __attribute__((ext_vector_type(8)));
typedef float f32x16 __attribute__((ext_vector_type(16)));

__device__ unsigned g_seq[(unsigned long long)NBLK * SEQW];   // 157 MB

#define SIG_SCALE  (-1.4426950408889634f)   // -log2(e)
#define TANH_SCALE ( 2.8853900817779268f)   // 2*log2(e)

__device__ __forceinline__ float rcpf(float x) {
    return __builtin_amdgcn_rcpf(x);
}
__device__ __forceinline__ float exp2f_(float x) {
    return __builtin_amdgcn_exp2f(x);
}
__device__ __forceinline__ unsigned packh(_Float16 a, _Float16 b) {
    union { _Float16 f; unsigned short s; } ua, ub;
    ua.f = a; ub.f = b;
    return (unsigned)ua.s | ((unsigned)ub.s << 16);
}

// One direction of one layer. seqR/seqW: [T][5][32] u32 pair-plane buffers
// (LDS or global per template use); xg: per-block x base (layer 0 only).
template <bool IS_L0, int NT, bool WRITE, bool STORE, bool G_R>
__device__ __forceinline__ void run_layer(
    const float* __restrict__ wih, const float* __restrict__ whh,
    const float* __restrict__ bih, const float* __restrict__ bhh,
    const unsigned* seqR, unsigned* seqW, const float* xg,
    float* outp, const int d, const int lane)
{
    const int lr   = lane & 31;    // A row / B,D column (batch)
    const int half = lane >> 5;    // k-half for A/B; D-row half bit

    // ---- A fragment: row lr = 8q+4h+g -> unit u_r = 2q+1-h, gate g ----
    const int q_r = lr >> 3;
    const int h_r = (lr >> 2) & 1;
    const int g   = lr & 3;        // 0=r 1=z 2=i_n 3=h_n
    const int u_r = 2 * q_r + 1 - h_r;
    const bool rv = (q_r < 3) && (u_r < 5);   // rows 16-19 & 24-31 zero

    f16x8 af;
#pragma unroll
    for (int e = 0; e < 8; e++) {
        const int k = 8 * half + e;           // elem e <-> k = 8*half + e
        float v = 0.f;
        if (rv) {
            if (!IS_L0) {
                if (k < 10) {                       // input channels
                    const int j = (k & 1) * 5 + (k >> 1);   // concat col
                    if (g == 0)      v = SIG_SCALE  * wih[u_r * 10 + j];
                    else if (g == 1) v = SIG_SCALE  * wih[(5 + u_r) * 10 + j];
                    else if (g == 2) v = TANH_SCALE * wih[(10 + u_r) * 10 + j];
                } else if (k < 15) {                // own-dir hidden
                    const int uh = k - 10;
                    if (g == 0)      v = SIG_SCALE  * whh[u_r * 5 + uh];
                    else if (g == 1) v = SIG_SCALE  * whh[(5 + u_r) * 5 + uh];
                    else if (g == 3) v = TANH_SCALE * whh[(10 + u_r) * 5 + uh];
                }
            } else {
                if (k == 0) {                       // input dim 1
                    if (g == 0)      v = SIG_SCALE  * wih[u_r];
                    else if (g == 1) v = SIG_SCALE  * wih[5 + u_r];
                    else if (g == 2) v = TANH_SCALE * wih[10 + u_r];
                } else if (k >= 10 && k < 15) {
                    const int uh = k - 10;
                    if (g == 0)      v = SIG_SCALE  * whh[u_r * 5 + uh];
                    else if (g == 1) v = SIG_SCALE  * whh[(5 + u_r) * 5 + uh];
                    else if (g == 3) v = TANH_SCALE * whh[(10 + u_r) * 5 + uh];
                }
            }
        }
        af[e] = (_Float16)v;
    }

    // ---- bias fragment (C): quad q -> unit u = 2q+1-half ----
    f32x16 bc;
#pragma unroll
    for (int q = 0; q < 4; q++) {
        const int u = 2 * q + 1 - half;
        float b0 = 0.f, b1 = 0.f, b2 = 0.f, b3 = 0.f;
        if (q < 3 && u < 5) {
            b0 = SIG_SCALE  * (bih[u] + bhh[u]);
            b1 = SIG_SCALE  * (bih[5 + u] + bhh[5 + u]);
            b2 = TANH_SCALE * bih[10 + u];
            b3 = TANH_SCALE * bhh[10 + u];
        }
        bc[4 * q + 0] = b0; bc[4 * q + 1] = b1;
        bc[4 * q + 2] = b2; bc[4 * q + 3] = b3;
    }

    // ---- step state ----
    const int sdir = d ? -1 : 1;
    const int p0   = d ? (T - 1) : 0;
    const unsigned* rbase = seqR + p0 * 160 + lr;
    const int r0off = half ? 128 : 0;            // half1 reads plane4 (ch8,9)
    _Float16* wbase = (_Float16*)seqW + p0 * 320 + lr * 2 + d;
    const int rstep = sdir * 160, wstep = sdir * 320;
    const int paddr = (lane ^ 32) << 2;          // cross-half partner

    // h0 = unit (1-half), h1 = unit (3-half), h2 = unit 4 (half1 only)
    float h0 = 0.f, h1 = 0.f, h2 = 0.f;
    unsigned pb1 = 0, pb2 = 0, pb3 = 0;          // h-slots of B (k10..15)

    auto step = [&](unsigned Bx0, unsigned Bx1, unsigned Bx2, unsigned Bx3) {
        union { f16x8 v; unsigned u[4]; } B;
        B.u[0] = Bx0;
        B.u[1] = half ? pb1 : Bx1;
        B.u[2] = half ? pb2 : Bx2;
        B.u[3] = half ? pb3 : Bx3;

        const f32x16 D = __builtin_amdgcn_mfma_f32_32x32x16_f16(af, B.v, bc, 0, 0, 0);

        // phase 1: all six sigmoid exps; per-unit shared rcp (2 rcp -> 1)
        const float er0 = exp2f_(D[0]), ez0 = exp2f_(D[1]);
        const float er1 = exp2f_(D[4]), ez1 = exp2f_(D[5]);
        const float er2 = exp2f_(D[8]), ez2 = exp2f_(D[9]);
        const float A0 = 1.f + er0, Z0 = 1.f + ez0;
        const float A1 = 1.f + er1, Z1 = 1.f + ez1;
        const float A2 = 1.f + er2, Z2 = 1.f + ez2;
        const float rp0 = rcpf(A0 * Z0);
        const float rp1 = rcpf(A1 * Z1);
        const float rp2 = rcpf(A2 * Z2);
        const float r0 = rp0 * Z0, z0 = rp0 * A0;
        const float r1 = rp1 * Z1, z1 = rp1 * A1;
        const float r2 = rp2 * Z2, z2 = rp2 * A2;

        // phase 2: u0/u1 tanh with pair-shared rcp, then h0/h1
        const float en0 = exp2f_(fmaf(r0, D[3], D[2]));
        const float en1 = exp2f_(fmaf(r1, D[7], D[6]));
        const float C0 = 1.f + en0, C1 = 1.f + en1;
        const float rpn = rcpf(C0 * C1);
        const float n0 = fmaf(-2.f, rpn * C1, 1.f);
        const float n1 = fmaf(-2.f, rpn * C0, 1.f);
        h0 = fmaf(z0, h0 - n0, n0);
        h1 = fmaf(z1, h1 - n1, n1);

        // pack + issue the single cross-half exchange early
        const _Float16 q0f = (_Float16)h0, q1f = (_Float16)h1;
        const unsigned pks = packh(q0f, q1f);
        const unsigned o = (unsigned)__builtin_amdgcn_ds_bpermute(paddr, (int)pks);

        // phase 3: u4 tanh (single rcp) hides the bpermute round-trip
        const float en2 = exp2f_(fmaf(r2, D[11], D[10]));
        const float n2 = fmaf(-2.f, rcpf(1.f + en2), 1.f);
        h2 = fmaf(z2, h2 - n2, n2);              // zero-rows on half0: harmless
        const _Float16 q2f = (_Float16)h2;

        pb1 = __builtin_amdgcn_perm(pks, o, 0x01000504u);  // [h_u0, h_u1]
        pb2 = __builtin_amdgcn_perm(pks, o, 0x03020706u);  // [h_u2, h_u3]
        pb3 = packh(q2f, (_Float16)0.f);                   // [h_u4, 0]

        if constexpr (WRITE) {
            wbase[(1 - half) * 64] = q0f;
            wbase[(3 - half) * 64] = q1f;
            if (half) wbase[4 * 64] = q2f;
            wbase += wstep;
        }
    };

    if constexpr (IS_L0) {
        // x direct from global, 1-step prefetch; lines cache-resident
        const float* xp = xg + lr * T + p0;
        float xf = *xp;
        for (int s = 0; s < NT; s++) {
            const unsigned xv = packh((_Float16)xf, (_Float16)0.f);
            if (s + 1 < NT) { xp += sdir; xf = *xp; }
            step(half ? 0u : xv, 0u, 0u, 0u);
        }
    } else if constexpr (!G_R) {
        // LDS reads, 1-step prefetch
        const unsigned* rb = rbase;
        unsigned c0 = rb[r0off], c1 = rb[32], c2 = rb[64], c3 = rb[96];
        for (int s = 0; s < NT; s++) {
            const unsigned t0 = c0, t1 = c1, t2 = c2, t3 = c3;
            if (s + 1 < NT) {
                rb += rstep;
                c0 = rb[r0off]; c1 = rb[32]; c2 = rb[64]; c3 = rb[96];
            }
            step(t0, t1, t2, t3);
        }
    } else if constexpr (NT == 1) {
        // layer-4 bwd: single step
        const unsigned a0 = rbase[r0off], a1 = rbase[32],
                       a2 = rbase[64],   a3 = rbase[96];
        step(a0, a1, a2, a3);
    } else {
        // global reads: two reg sets, prefetch 2 positions ahead (vmcnt)
        const unsigned* rn = rbase;
        unsigned a0 = rn[r0off], a1 = rn[32], a2 = rn[64], a3 = rn[96];
        rn += rstep;
        unsigned b0 = rn[r0off], b1 = rn[32], b2 = rn[64], b3 = rn[96];
        rn += rstep;
        for (int s = 0; s < NT; s += 2) {
            step(a0, a1, a2, a3);
            if (s + 2 < NT) {
                a0 = rn[r0off]; a1 = rn[32]; a2 = rn[64]; a3 = rn[96];
                rn += rstep;
            }
            step(b0, b1, b2, b3);
            if (s + 3 < NT) {
                b0 = rn[r0off]; b1 = rn[32]; b2 = rn[64]; b3 = rn[96];
                rn += rstep;
            }
        }
    }

    if constexpr (STORE) {               // ys[T-1] for this direction
        outp[1 - half] = h0;
        outp[3 - half] = h1;
        if (half) outp[4] = h2;
    }
}

__global__ void __launch_bounds__(128, 4) gru_all(
    const float* __restrict__ x,
    const float* __restrict__ wih0, const float* __restrict__ whh0,
    const float* __restrict__ bih0, const float* __restrict__ bhh0,
    const float* __restrict__ wihL, const float* __restrict__ whhL,
    const float* __restrict__ bihL, const float* __restrict__ bhhL,
    float* __restrict__ out)
{
    __shared__ unsigned S[T][5][32];             // 19200 B -> 8 blocks/CU

    const int tid  = threadIdx.x;
    const int d    = tid >> 6;                   // wave0 = fwd, wave1 = bwd
    const int lane = tid & 63;
    const int lr   = lane & 63 & 31;
    const long base = (long)blockIdx.x * 32;

    const float* xg = x + base * T;
    unsigned* G = g_seq + (unsigned long long)blockIdx.x * SEQW;

    // L0: x -> S
    run_layer<true, T, true, false, false>(
        wih0 + d * 15, whh0 + d * 75, bih0 + d * 15, bhh0 + d * 15,
        nullptr, &S[0][0][0], xg, nullptr, d, lane);
    __syncthreads();

    // L1: S -> G
    run_layer<false, T, true, false, false>(
        wihL + (0 + d) * 150, whhL + (0 + d) * 75, bihL + (0 + d) * 15, bhhL + (0 + d) * 15,
        &S[0][0][0], G, nullptr, nullptr, d, lane);
    __syncthreads();

    // L2: G -> S
    run_layer<false, T, true, false, true>(
        wihL + (2 + d) * 150, whhL + (2 + d) * 75, bihL + (2 + d) * 15, bhhL + (2 + d) * 15,
        G, &S[0][0][0], nullptr, nullptr, d, lane);
    __syncthreads();

    // L3: S -> G
    run_layer<false, T, true, false, false>(
        wihL + (4 + d) * 150, whhL + (4 + d) * 75, bihL + (4 + d) * 15, bhhL + (4 + d) * 15,
        &S[0][0][0], G, nullptr, nullptr, d, lane);
    __syncthreads();

    // L4: G -> out; fwd runs 30 steps, bwd needs only its first step
    {
        float* op = out + (base + lr) * 10 + d * 5;
        if (d == 0)
            run_layer<false, T, false, true, true>(
                wihL + 6 * 150, whhL + 6 * 75, bihL + 6 * 15, bhhL + 6 * 15,
                G, nullptr, nullptr, op, d, lane);
        else
            run_layer<false, 1, false, true, true>(
                wihL + 7 * 150, whhL + 7 * 75, bihL + 7 * 15, bhhL + 7 * 15,
                G, nullptr, nullptr, op, d, lane);
    }
}

extern "C" void kernel_launch(void* const* d_in, const int* in_sizes, int n_in,
                              void* d_out, int out_size, void* d_ws, size_t ws_size,
                              hipStream_t stream) {
    const float* x    = (const float*)d_in[0];
    const float* wih0 = (const float*)d_in[1];
    const float* whh0 = (const float*)d_in[2];
    const float* bih0 = (const float*)d_in[3];
    const float* bhh0 = (const float*)d_in[4];
    const float* wihL = (const float*)d_in[5];
    const float* whhL = (const float*)d_in[6];
    const float* bihL = (const float*)d_in[7];
    const float* bhhL = (const float*)d_in[8];
    float* out = (float*)d_out;

    gru_all<<<NBLK, 128, 0, stream>>>(x, wih0, whh0, bih0, bhh0,
                                      wihL, whhL, bihL, bhhL, out);
}

// Round 11
// 437.287 us; speedup vs baseline: 2.7700x; 1.0370x over previous
//
#include <hip/hip_runtime.h>

// MFMA-based fully-fused 5-layer bidirectional GRU -- exchange-free version.
//
// r10 lesson: shared-rcp coupled independent chains -> slower. The kernel is
// recurrence-chain-bound (issue ~355cy/step, wall ~1800cy; 4 waves cover 76%;
// more waves blocked by L2 capacity per r9). This round removes the last
// memory-pipe op from the chain: the per-step ds_bpermute h-exchange.
//
// Key idea: co-design B's k-layout with D ownership. D layout (verified r2):
// row = 4u+g, so half0 lanes own units {0,2,4}, half1 own {1,3}. Place h
// k-slots to match: k5,6,7 = h_u0,u2,u4 (half0's elements 5..7), k13,14 =
// h_u1,u3 (half1's elements 5..6). x channels fill k0..4 & k8..12 in pair-
// plane order: k -> idx = (k<8 ? k : k-3), concat col j = (idx&1)*5+(idx>>1).
// Every lane feeds B h-slots from ITS OWN registers -> no bpermute, no merge
// selects. B dwords are built with two layer-constant v_perm selectors
// (operating on prefetched LDS planes, off-chain) + ONE on-chain perm.
//
// A (32x16 const): row = 4u+g, g in {r,z,i_n,h_n}, rows 20-31 zero; same
// k-rule as B (self-consistent). C = bias fragment, quad q -> u = 2q+half
// (r2-verified; q2/half1 -> u5 zeroed, h2 dead on half1). i_n/h_n separate
// rows so n = tanh(i_n + r*h_n) exact; exp2 scales folded into weights.
//
// Structure (r8, verified): block = 2 waves (wave0 fwd, wave1 bwd), 32 batch.
// One 19.2KB LDS buffer + one 19.2KB global buffer per block (8 blocks/CU,
// 4.9MB/XCD = the L2-capacity optimum per r9). Dataflow: L0: x->S; L1: S->G;
// L2: G->S; L3: S->G; L4: G->out (bwd needs only its first step). LDS reads
// prefetched 1 step, global reads 2 steps ahead.
// Sequences: f16 pair-planes seq[t][unit][batch], fwd lo / bwd hi halfword.

#define NB 262144
#define T 30
#define NBLK (NB / 32)
#define SEQW (T * 5 * 32)          // u32 per per-block sequence buffer

typedef _Float16 f16x8 __attribute__((ext_vector_type(8)));
typedef float f32x16 __attribute__((ext_vector_type(16)));

__device__ unsigned g_seq[(unsigned long long)NBLK * SEQW];   // 157 MB

#define SIG_SCALE  (-1.4426950408889634f)   // -log2(e)
#define TANH_SCALE ( 2.8853900817779268f)   // 2*log2(e)

__device__ __forceinline__ float sig_s(float xs) {
    // x pre-scaled by -log2e: sigmoid(orig) = 1/(1+2^x)
    return __builtin_amdgcn_rcpf(1.0f + __builtin_amdgcn_exp2f(xs));
}
__device__ __forceinline__ float tanh_s(float xs) {
    // x pre-scaled by 2*log2e: tanh(orig) = 1 - 2/(1+2^x)
    return fmaf(-2.0f, __builtin_amdgcn_rcpf(1.0f + __builtin_amdgcn_exp2f(xs)), 1.0f);
}
__device__ __forceinline__ unsigned hbits(_Float16 a) {
    union { _Float16 f; unsigned short s; } u; u.f = a;
    return (unsigned)u.s;
}
__device__ __forceinline__ unsigned packh(_Float16 a, _Float16 b) {
    return hbits(a) | (hbits(b) << 16);
}

// One direction of one layer. seqR/seqW: [T][5][32] u32 pair-plane buffers
// (LDS or global per G_R); xg: per-block x base (layer 0 only).
template <bool IS_L0, int NT, bool WRITE, bool STORE, bool G_R>
__device__ __forceinline__ void run_layer(
    const float* __restrict__ wih, const float* __restrict__ whh,
    const float* __restrict__ bih, const float* __restrict__ bhh,
    const unsigned* seqR, unsigned* seqW, const float* xg,
    float* outp, const int d, const int lane)
{
    const int lr   = lane & 31;    // A row / B,D column (batch)
    const int half = lane >> 5;    // k-half for A/B; D-row half bit

    // ---- A fragment: row lr = 4u+g ----
    const int u_r = lr >> 2;
    const int g   = lr & 3;        // 0=r 1=z 2=i_n 3=h_n
    const bool rv = lr < 20;       // rows 20-31 zero

    f16x8 af;
#pragma unroll
    for (int e = 0; e < 8; e++) {
        const int k = 8 * half + e;           // elem e <-> k = 8*half + e
        float v = 0.f;
        if (rv) {
            if (!IS_L0) {
                if (k <= 4 || (k >= 8 && k <= 12)) {      // x channels
                    const int idx = (k < 8) ? k : (k - 3);
                    const int j = (idx & 1) * 5 + (idx >> 1);   // concat col
                    if (g == 0)      v = SIG_SCALE  * wih[u_r * 10 + j];
                    else if (g == 1) v = SIG_SCALE  * wih[(5 + u_r) * 10 + j];
                    else if (g == 2) v = TANH_SCALE * wih[(10 + u_r) * 10 + j];
                } else if (k >= 5 && k <= 7) {            // h_u0,u2,u4
                    const int uh = 2 * (k - 5);
                    if (g == 0)      v = SIG_SCALE  * whh[u_r * 5 + uh];
                    else if (g == 1) v = SIG_SCALE  * whh[(5 + u_r) * 5 + uh];
                    else if (g == 3) v = TANH_SCALE * whh[(10 + u_r) * 5 + uh];
                } else if (k == 13 || k == 14) {          // h_u1,u3
                    const int uh = 2 * (k - 13) + 1;
                    if (g == 0)      v = SIG_SCALE  * whh[u_r * 5 + uh];
                    else if (g == 1) v = SIG_SCALE  * whh[(5 + u_r) * 5 + uh];
                    else if (g == 3) v = TANH_SCALE * whh[(10 + u_r) * 5 + uh];
                }
            } else {
                if (k == 0) {                             // input dim 1
                    if (g == 0)      v = SIG_SCALE  * wih[u_r];
                    else if (g == 1) v = SIG_SCALE  * wih[5 + u_r];
                    else if (g == 2) v = TANH_SCALE * wih[10 + u_r];
                } else if (k >= 5 && k <= 7) {
                    const int uh = 2 * (k - 5);
                    if (g == 0)      v = SIG_SCALE  * whh[u_r * 5 + uh];
                    else if (g == 1) v = SIG_SCALE  * whh[(5 + u_r) * 5 + uh];
                    else if (g == 3) v = TANH_SCALE * whh[(10 + u_r) * 5 + uh];
                } else if (k == 13 || k == 14) {
                    const int uh = 2 * (k - 13) + 1;
                    if (g == 0)      v = SIG_SCALE  * whh[u_r * 5 + uh];
                    else if (g == 1) v = SIG_SCALE  * whh[(5 + u_r) * 5 + uh];
                    else if (g == 3) v = TANH_SCALE * whh[(10 + u_r) * 5 + uh];
                }
            }
        }
        af[e] = (_Float16)v;
    }

    // ---- bias fragment (C): quad q -> unit u = 2q+half (r2-verified) ----
    f32x16 bc;
#pragma unroll
    for (int q = 0; q < 4; q++) {
        const int u = 2 * q + half;
        float b0 = 0.f, b1 = 0.f, b2 = 0.f, b3 = 0.f;
        if (q < 3 && u < 5) {
            b0 = SIG_SCALE  * (bih[u] + bhh[u]);
            b1 = SIG_SCALE  * (bih[5 + u] + bhh[5 + u]);
            b2 = TANH_SCALE * bih[10 + u];
            b3 = TANH_SCALE * bhh[10 + u];
        }
        bc[4 * q + 0] = b0; bc[4 * q + 1] = b1;
        bc[4 * q + 2] = b2; bc[4 * q + 3] = b3;
    }

    // ---- B-assembly selectors (layer-constant; perm: sel<4 -> 2nd arg) ----
    // u[0] = half0: p_a              | half1: (p_a.hi, p_b.lo)
    // u[1] = half0: p_b              | half1: (p_b.hi, p_c.lo)
    // u[2] = half0: (p_c.lo, h0bits) | half1: (p_c.hi, h0bits)
    const unsigned S01 = half ? 0x05040302u : 0x03020100u;
    const unsigned S2  = half ? 0x05040302u : 0x05040100u;

    // ---- step state ----
    const int sdir = d ? -1 : 1;
    const int p0   = d ? (T - 1) : 0;
    // half0 reads planes 0,1,2; half1 reads planes 2,3,4 (offsets 0/32/64)
    const unsigned* rbase = seqR + p0 * 160 + lr + (half ? 64 : 0);
    _Float16* wbase = (_Float16*)seqW + p0 * 320 + lr * 2 + d;
    const int rstep = sdir * 160, wstep = sdir * 320;

    // h0 = unit (0+half... u=2i+half): h0=u(half), h1=u(2+half), h2=u4 (half0)
    float h0 = 0.f, h1 = 0.f, h2 = 0.f;
    unsigned hw2 = 0, hw3 = 0;     // h0 bits (low16); pack(h1,h2)

    auto step = [&](unsigned pa, unsigned pb, unsigned pc, unsigned xv) {
        union { f16x8 v; unsigned u[4]; } B;
        if constexpr (!IS_L0) {
            B.u[0] = __builtin_amdgcn_perm(pb, pa, S01);
            B.u[1] = __builtin_amdgcn_perm(pc, pb, S01);
            B.u[2] = __builtin_amdgcn_perm(hw2, pc, S2);
        } else {
            B.u[0] = half ? 0u : xv;
            B.u[1] = 0u;
            B.u[2] = hw2 << 16;            // (0, h0)
        }
        B.u[3] = hw3;                      // (h1, h2); k15/k7-dead rows are 0 in A

        const f32x16 D = __builtin_amdgcn_mfma_f32_32x32x16_f16(af, B.v, bc, 0, 0, 0);

        // activations (independent chains, r8 form): quad q = unit 2q+half
        float r, z, n;
        r = sig_s(D[0]); z = sig_s(D[1]);
        n = tanh_s(fmaf(r, D[3], D[2]));
        h0 = fmaf(z, h0 - n, n);
        r = sig_s(D[4]); z = sig_s(D[5]);
        n = tanh_s(fmaf(r, D[7], D[6]));
        h1 = fmaf(z, h1 - n, n);
        r = sig_s(D[8]); z = sig_s(D[9]);
        n = tanh_s(fmaf(r, D[11], D[10]));
        h2 = fmaf(z, h2 - n, n);           // zero rows on half1: harmless 0

        const _Float16 q0f = (_Float16)h0, q1f = (_Float16)h1, q2f = (_Float16)h2;
        hw2 = hbits(q0f);
        hw3 = packh(q1f, q2f);

        if constexpr (WRITE) {
            wbase[half * 64]       = q0f;          // plane u = half
            wbase[(2 + half) * 64] = q1f;          // plane u = 2+half
            if (!half) wbase[4 * 64] = q2f;        // plane u = 4
            wbase += wstep;
        }
    };

    if constexpr (IS_L0) {
        // x direct from global, 1-step prefetch; lines cache-resident
        const float* xp = xg + lr * T + p0;
        float xf = *xp;
        for (int s = 0; s < NT; s++) {
            const unsigned xv = hbits((_Float16)xf);
            if (s + 1 < NT) { xp += sdir; xf = *xp; }
            step(0u, 0u, 0u, xv);
        }
    } else if constexpr (!G_R) {
        // LDS reads, 1-step prefetch
        const unsigned* rb = rbase;
        unsigned a0 = rb[0], a1 = rb[32], a2 = rb[64];
        for (int s = 0; s < NT; s++) {
            const unsigned t0 = a0, t1 = a1, t2 = a2;
            if (s + 1 < NT) {
                rb += rstep;
                a0 = rb[0]; a1 = rb[32]; a2 = rb[64];
            }
            step(t0, t1, t2, 0u);
        }
    } else if constexpr (NT == 1) {
        // layer-4 bwd: single step
        step(rbase[0], rbase[32], rbase[64], 0u);
    } else {
        // global reads: two reg sets, prefetch 2 positions ahead (vmcnt)
        const unsigned* rn = rbase;
        unsigned a0 = rn[0], a1 = rn[32], a2 = rn[64];
        rn += rstep;
        unsigned b0 = rn[0], b1 = rn[32], b2 = rn[64];
        rn += rstep;
        for (int s = 0; s < NT; s += 2) {
            step(a0, a1, a2, 0u);
            if (s + 2 < NT) {
                a0 = rn[0]; a1 = rn[32]; a2 = rn[64];
                rn += rstep;
            }
            step(b0, b1, b2, 0u);
            if (s + 3 < NT) {
                b0 = rn[0]; b1 = rn[32]; b2 = rn[64];
                rn += rstep;
            }
        }
    }

    if constexpr (STORE) {               // ys[T-1] for this direction
        outp[half]     = h0;
        outp[2 + half] = h1;
        if (!half) outp[4] = h2;
    }
}

__global__ void __launch_bounds__(128, 4) gru_all(
    const float* __restrict__ x,
    const float* __restrict__ wih0, const float* __restrict__ whh0,
    const float* __restrict__ bih0, const float* __restrict__ bhh0,
    const float* __restrict__ wihL, const float* __restrict__ whhL,
    const float* __restrict__ bihL, const float* __restrict__ bhhL,
    float* __restrict__ out)
{
    __shared__ unsigned S[T][5][32];             // 19200 B -> 8 blocks/CU

    const int tid  = threadIdx.x;
    const int d    = tid >> 6;                   // wave0 = fwd, wave1 = bwd
    const int lane = tid & 63;
    const int lr   = lane & 31;
    const long base = (long)blockIdx.x * 32;

    const float* xg = x + base * T;
    unsigned* G = g_seq + (unsigned long long)blockIdx.x * SEQW;

    // L0: x -> S
    run_layer<true, T, true, false, false>(
        wih0 + d * 15, whh0 + d * 75, bih0 + d * 15, bhh0 + d * 15,
        nullptr, &S[0][0][0], xg, nullptr, d, lane);
    __syncthreads();

    // L1: S -> G
    run_layer<false, T, true, false, false>(
        wihL + (0 + d) * 150, whhL + (0 + d) * 75, bihL + (0 + d) * 15, bhhL + (0 + d) * 15,
        &S[0][0][0], G, nullptr, nullptr, d, lane);
    __syncthreads();

    // L2: G -> S
    run_layer<false, T, true, false, true>(
        wihL + (2 + d) * 150, whhL + (2 + d) * 75, bihL + (2 + d) * 15, bhhL + (2 + d) * 15,
        G, &S[0][0][0], nullptr, nullptr, d, lane);
    __syncthreads();

    // L3: S -> G
    run_layer<false, T, true, false, false>(
        wihL + (4 + d) * 150, whhL + (4 + d) * 75, bihL + (4 + d) * 15, bhhL + (4 + d) * 15,
        &S[0][0][0], G, nullptr, nullptr, d, lane);
    __syncthreads();

    // L4: G -> out; fwd runs 30 steps, bwd needs only its first step
    {
        float* op = out + (base + lr) * 10 + d * 5;
        if (d == 0)
            run_layer<false, T, false, true, true>(
                wihL + 6 * 150, whhL + 6 * 75, bihL + 6 * 15, bhhL + 6 * 15,
                G, nullptr, nullptr, op, d, lane);
        else
            run_layer<false, 1, false, true, true>(
                wihL + 7 * 150, whhL + 7 * 75, bihL + 7 * 15, bhhL + 7 * 15,
                G, nullptr, nullptr, op, d, lane);
    }
}

extern "C" void kernel_launch(void* const* d_in, const int* in_sizes, int n_in,
                              void* d_out, int out_size, void* d_ws, size_t ws_size,
                              hipStream_t stream) {
    const float* x    = (const float*)d_in[0];
    const float* wih0 = (const float*)d_in[1];
    const float* whh0 = (const float*)d_in[2];
    const float* bih0 = (const float*)d_in[3];
    const float* bhh0 = (const float*)d_in[4];
    const float* wihL = (const float*)d_in[5];
    const float* whhL = (const float*)d_in[6];
    const float* bihL = (const float*)d_in[7];
    const float* bhhL = (const float*)d_in[8];
    float* out = (float*)d_out;

    gru_all<<<NBLK, 128, 0, stream>>>(x, wih0, whh0, bih0, bhh0,
                                      wihL, whhL, bihL, bhhL, out);
}

// Round 12
// 430.189 us; speedup vs baseline: 2.8157x; 1.0165x over previous
//
#include <hip/hip_runtime.h>

// MFMA-based fully-fused 5-layer bidirectional GRU -- exchange-free + deep
// prefetch.
//
// r11 (403us, VALUBusy 76%) model: per-SIMD wall 446cy/wave-step-slot, issue
// 338cy -> 4 waves cover 76%. Residual stall candidates: G-read L2 misses
// (FETCH 130MB; 4.9MB/XCD > 4MB L2) with only-just-sufficient 2-step
// prefetch lead, store-drain at layer barriers, MFMA head-of-step latency.
// This round: G-read prefetch 2->4 steps (4 reg sets), L0 x-prefetch 1->2.
// Pure latency-coverage probe; all math byte-identical to r11.
//
// Exchange-free B layout (r11, verified): D row = 4u+g -> half0 owns units
// {0,2,4}, half1 {1,3}. B h-slots placed to match ownership: k5,6,7 =
// h_u0,u2,u4 (half0 elems 5..7), k13,14 = h_u1,u3 (half1 elems 5..6); x
// channels at k0..4 & k8..12, idx=(k<8?k:k-3), concat col j=(idx&1)*5+(idx>>1).
// No cross-lane h movement at all. B dwords via 2 layer-constant v_perm
// (off-chain) + 1 on-chain perm.
//
// A (32x16 const): row = 4u+g, g in {r,z,i_n,h_n}, rows 20-31 zero; same
// k-rule as B. C = bias fragment, quad q -> u = 2q+half (r2-verified).
// i_n/h_n separate rows so n = tanh(i_n + r*h_n) exact; exp2 scales folded.
//
// Structure (r8): block = 2 waves (wave0 fwd, wave1 bwd), 32 batch cols.
// One 19.2KB LDS buffer + one 19.2KB global buffer (8 blocks/CU, 4.9MB/XCD).
// Dataflow: L0: x->S; L1: S->G; L2: G->S; L3: S->G; L4: G->out (bwd: 1 step).
// Sequences: f16 pair-planes seq[t][unit][batch], fwd lo / bwd hi halfword.

#define NB 262144
#define T 30
#define NBLK (NB / 32)
#define SEQW (T * 5 * 32)          // u32 per per-block sequence buffer

typedef _Float16 f16x8 __attribute__((ext_vector_type(8)));
typedef float f32x16 __attribute__((ext_vector_type(16)));

__device__ unsigned g_seq[(unsigned long long)NBLK * SEQW];   // 157 MB

#define SIG_SCALE  (-1.4426950408889634f)   // -log2(e)
#define TANH_SCALE ( 2.8853900817779268f)   // 2*log2(e)

__device__ __forceinline__ float sig_s(float xs) {
    // x pre-scaled by -log2e: sigmoid(orig) = 1/(1+2^x)
    return __builtin_amdgcn_rcpf(1.0f + __builtin_amdgcn_exp2f(xs));
}
__device__ __forceinline__ float tanh_s(float xs) {
    // x pre-scaled by 2*log2e: tanh(orig) = 1 - 2/(1+2^x)
    return fmaf(-2.0f, __builtin_amdgcn_rcpf(1.0f + __builtin_amdgcn_exp2f(xs)), 1.0f);
}
__device__ __forceinline__ unsigned hbits(_Float16 a) {
    union { _Float16 f; unsigned short s; } u; u.f = a;
    return (unsigned)u.s;
}
__device__ __forceinline__ unsigned packh(_Float16 a, _Float16 b) {
    return hbits(a) | (hbits(b) << 16);
}

// One direction of one layer. seqR/seqW: [T][5][32] u32 pair-plane buffers
// (LDS or global per G_R); xg: per-block x base (layer 0 only).
template <bool IS_L0, int NT, bool WRITE, bool STORE, bool G_R>
__device__ __forceinline__ void run_layer(
    const float* __restrict__ wih, const float* __restrict__ whh,
    const float* __restrict__ bih, const float* __restrict__ bhh,
    const unsigned* seqR, unsigned* seqW, const float* xg,
    float* outp, const int d, const int lane)
{
    const int lr   = lane & 31;    // A row / B,D column (batch)
    const int half = lane >> 5;    // k-half for A/B; D-row half bit

    // ---- A fragment: row lr = 4u+g ----
    const int u_r = lr >> 2;
    const int g   = lr & 3;        // 0=r 1=z 2=i_n 3=h_n
    const bool rv = lr < 20;       // rows 20-31 zero

    f16x8 af;
#pragma unroll
    for (int e = 0; e < 8; e++) {
        const int k = 8 * half + e;           // elem e <-> k = 8*half + e
        float v = 0.f;
        if (rv) {
            if (!IS_L0) {
                if (k <= 4 || (k >= 8 && k <= 12)) {      // x channels
                    const int idx = (k < 8) ? k : (k - 3);
                    const int j = (idx & 1) * 5 + (idx >> 1);   // concat col
                    if (g == 0)      v = SIG_SCALE  * wih[u_r * 10 + j];
                    else if (g == 1) v = SIG_SCALE  * wih[(5 + u_r) * 10 + j];
                    else if (g == 2) v = TANH_SCALE * wih[(10 + u_r) * 10 + j];
                } else if (k >= 5 && k <= 7) {            // h_u0,u2,u4
                    const int uh = 2 * (k - 5);
                    if (g == 0)      v = SIG_SCALE  * whh[u_r * 5 + uh];
                    else if (g == 1) v = SIG_SCALE  * whh[(5 + u_r) * 5 + uh];
                    else if (g == 3) v = TANH_SCALE * whh[(10 + u_r) * 5 + uh];
                } else if (k == 13 || k == 14) {          // h_u1,u3
                    const int uh = 2 * (k - 13) + 1;
                    if (g == 0)      v = SIG_SCALE  * whh[u_r * 5 + uh];
                    else if (g == 1) v = SIG_SCALE  * whh[(5 + u_r) * 5 + uh];
                    else if (g == 3) v = TANH_SCALE * whh[(10 + u_r) * 5 + uh];
                }
            } else {
                if (k == 0) {                             // input dim 1
                    if (g == 0)      v = SIG_SCALE  * wih[u_r];
                    else if (g == 1) v = SIG_SCALE  * wih[5 + u_r];
                    else if (g == 2) v = TANH_SCALE * wih[10 + u_r];
                } else if (k >= 5 && k <= 7) {
                    const int uh = 2 * (k - 5);
                    if (g == 0)      v = SIG_SCALE  * whh[u_r * 5 + uh];
                    else if (g == 1) v = SIG_SCALE  * whh[(5 + u_r) * 5 + uh];
                    else if (g == 3) v = TANH_SCALE * whh[(10 + u_r) * 5 + uh];
                } else if (k == 13 || k == 14) {
                    const int uh = 2 * (k - 13) + 1;
                    if (g == 0)      v = SIG_SCALE  * whh[u_r * 5 + uh];
                    else if (g == 1) v = SIG_SCALE  * whh[(5 + u_r) * 5 + uh];
                    else if (g == 3) v = TANH_SCALE * whh[(10 + u_r) * 5 + uh];
                }
            }
        }
        af[e] = (_Float16)v;
    }

    // ---- bias fragment (C): quad q -> unit u = 2q+half (r2-verified) ----
    f32x16 bc;
#pragma unroll
    for (int q = 0; q < 4; q++) {
        const int u = 2 * q + half;
        float b0 = 0.f, b1 = 0.f, b2 = 0.f, b3 = 0.f;
        if (q < 3 && u < 5) {
            b0 = SIG_SCALE  * (bih[u] + bhh[u]);
            b1 = SIG_SCALE  * (bih[5 + u] + bhh[5 + u]);
            b2 = TANH_SCALE * bih[10 + u];
            b3 = TANH_SCALE * bhh[10 + u];
        }
        bc[4 * q + 0] = b0; bc[4 * q + 1] = b1;
        bc[4 * q + 2] = b2; bc[4 * q + 3] = b3;
    }

    // ---- B-assembly selectors (layer-constant; perm: sel<4 -> 2nd arg) ----
    const unsigned S01 = half ? 0x05040302u : 0x03020100u;
    const unsigned S2  = half ? 0x05040302u : 0x05040100u;

    // ---- step state ----
    const int sdir = d ? -1 : 1;
    const int p0   = d ? (T - 1) : 0;
    // half0 reads planes 0,1,2; half1 reads planes 2,3,4 (offsets 0/32/64)
    const unsigned* rbase = seqR + p0 * 160 + lr + (half ? 64 : 0);
    _Float16* wbase = (_Float16*)seqW + p0 * 320 + lr * 2 + d;
    const int rstep = sdir * 160, wstep = sdir * 320;

    // h0 = u(half), h1 = u(2+half), h2 = u4 (half0; dead on half1)
    float h0 = 0.f, h1 = 0.f, h2 = 0.f;
    unsigned hw2 = 0, hw3 = 0;     // h0 bits (low16); pack(h1,h2)

    auto step = [&](unsigned pa, unsigned pb, unsigned pc, unsigned xv) {
        union { f16x8 v; unsigned u[4]; } B;
        if constexpr (!IS_L0) {
            B.u[0] = __builtin_amdgcn_perm(pb, pa, S01);
            B.u[1] = __builtin_amdgcn_perm(pc, pb, S01);
            B.u[2] = __builtin_amdgcn_perm(hw2, pc, S2);
        } else {
            B.u[0] = half ? 0u : xv;
            B.u[1] = 0u;
            B.u[2] = hw2 << 16;            // (0, h0)
        }
        B.u[3] = hw3;                      // (h1, h2); dead k-rows are 0 in A

        const f32x16 D = __builtin_amdgcn_mfma_f32_32x32x16_f16(af, B.v, bc, 0, 0, 0);

        // activations (independent chains): quad q = unit 2q+half
        float r, z, n;
        r = sig_s(D[0]); z = sig_s(D[1]);
        n = tanh_s(fmaf(r, D[3], D[2]));
        h0 = fmaf(z, h0 - n, n);
        r = sig_s(D[4]); z = sig_s(D[5]);
        n = tanh_s(fmaf(r, D[7], D[6]));
        h1 = fmaf(z, h1 - n, n);
        r = sig_s(D[8]); z = sig_s(D[9]);
        n = tanh_s(fmaf(r, D[11], D[10]));
        h2 = fmaf(z, h2 - n, n);           // zero rows on half1: harmless 0

        const _Float16 q0f = (_Float16)h0, q1f = (_Float16)h1, q2f = (_Float16)h2;
        hw2 = hbits(q0f);
        hw3 = packh(q1f, q2f);

        if constexpr (WRITE) {
            wbase[half * 64]       = q0f;          // plane u = half
            wbase[(2 + half) * 64] = q1f;          // plane u = 2+half
            if (!half) wbase[4 * 64] = q2f;        // plane u = 4
            wbase += wstep;
        }
    };

    if constexpr (IS_L0) {
        // x direct from global, 2-step prefetch
        const float* xp = xg + lr * T + p0;
        float xf0 = xp[0];
        float xf1 = (NT > 1) ? xp[sdir] : 0.f;
        xp += 2 * sdir;
        for (int s = 0; s < NT; s++) {
            const unsigned xv = hbits((_Float16)xf0);
            xf0 = xf1;
            if (s + 2 < NT) { xf1 = *xp; xp += sdir; }
            step(0u, 0u, 0u, xv);
        }
    } else if constexpr (!G_R) {
        // LDS reads, 1-step prefetch (LDS latency deeply covered)
        const unsigned* rb = rbase;
        unsigned a0 = rb[0], a1 = rb[32], a2 = rb[64];
        for (int s = 0; s < NT; s++) {
            const unsigned t0 = a0, t1 = a1, t2 = a2;
            if (s + 1 < NT) {
                rb += rstep;
                a0 = rb[0]; a1 = rb[32]; a2 = rb[64];
            }
            step(t0, t1, t2, 0u);
        }
    } else if constexpr (NT == 1) {
        // layer-4 bwd: single step
        step(rbase[0], rbase[32], rbase[64], 0u);
    } else {
        // global reads: FOUR reg sets, prefetch 4 positions ahead (vmcnt) --
        // covers HBM-miss latency (~900cy) with ~4-step lead
        const unsigned* rn = rbase;
        unsigned a0 = rn[0], a1 = rn[32], a2 = rn[64]; rn += rstep;
        unsigned b0 = rn[0], b1 = rn[32], b2 = rn[64]; rn += rstep;
        unsigned c0 = rn[0], c1 = rn[32], c2 = rn[64]; rn += rstep;
        unsigned e0 = rn[0], e1 = rn[32], e2 = rn[64]; rn += rstep;
        for (int s = 0; s < NT; s += 4) {
            step(a0, a1, a2, 0u);
            if (s + 4 < NT) { a0 = rn[0]; a1 = rn[32]; a2 = rn[64]; rn += rstep; }
            if (s + 1 < NT) {
                step(b0, b1, b2, 0u);
                if (s + 5 < NT) { b0 = rn[0]; b1 = rn[32]; b2 = rn[64]; rn += rstep; }
            }
            if (s + 2 < NT) {
                step(c0, c1, c2, 0u);
                if (s + 6 < NT) { c0 = rn[0]; c1 = rn[32]; c2 = rn[64]; rn += rstep; }
            }
            if (s + 3 < NT) {
                step(e0, e1, e2, 0u);
                if (s + 7 < NT) { e0 = rn[0]; e1 = rn[32]; e2 = rn[64]; rn += rstep; }
            }
        }
    }

    if constexpr (STORE) {               // ys[T-1] for this direction
        outp[half]     = h0;
        outp[2 + half] = h1;
        if (!half) outp[4] = h2;
    }
}

__global__ void __launch_bounds__(128, 4) gru_all(
    const float* __restrict__ x,
    const float* __restrict__ wih0, const float* __restrict__ whh0,
    const float* __restrict__ bih0, const float* __restrict__ bhh0,
    const float* __restrict__ wihL, const float* __restrict__ whhL,
    const float* __restrict__ bihL, const float* __restrict__ bhhL,
    float* __restrict__ out)
{
    __shared__ unsigned S[T][5][32];             // 19200 B -> 8 blocks/CU

    const int tid  = threadIdx.x;
    const int d    = tid >> 6;                   // wave0 = fwd, wave1 = bwd
    const int lane = tid & 63;
    const int lr   = lane & 31;
    const long base = (long)blockIdx.x * 32;

    const float* xg = x + base * T;
    unsigned* G = g_seq + (unsigned long long)blockIdx.x * SEQW;

    // L0: x -> S
    run_layer<true, T, true, false, false>(
        wih0 + d * 15, whh0 + d * 75, bih0 + d * 15, bhh0 + d * 15,
        nullptr, &S[0][0][0], xg, nullptr, d, lane);
    __syncthreads();

    // L1: S -> G
    run_layer<false, T, true, false, false>(
        wihL + (0 + d) * 150, whhL + (0 + d) * 75, bihL + (0 + d) * 15, bhhL + (0 + d) * 15,
        &S[0][0][0], G, nullptr, nullptr, d, lane);
    __syncthreads();

    // L2: G -> S
    run_layer<false, T, true, false, true>(
        wihL + (2 + d) * 150, whhL + (2 + d) * 75, bihL + (2 + d) * 15, bhhL + (2 + d) * 15,
        G, &S[0][0][0], nullptr, nullptr, d, lane);
    __syncthreads();

    // L3: S -> G
    run_layer<false, T, true, false, false>(
        wihL + (4 + d) * 150, whhL + (4 + d) * 75, bihL + (4 + d) * 15, bhhL + (4 + d) * 15,
        &S[0][0][0], G, nullptr, nullptr, d, lane);
    __syncthreads();

    // L4: G -> out; fwd runs 30 steps, bwd needs only its first step
    {
        float* op = out + (base + lr) * 10 + d * 5;
        if (d == 0)
            run_layer<false, T, false, true, true>(
                wihL + 6 * 150, whhL + 6 * 75, bihL + 6 * 15, bhhL + 6 * 15,
                G, nullptr, nullptr, op, d, lane);
        else
            run_layer<false, 1, false, true, true>(
                wihL + 7 * 150, whhL + 7 * 75, bihL + 7 * 15, bhhL + 7 * 15,
                G, nullptr, nullptr, op, d, lane);
    }
}

extern "C" void kernel_launch(void* const* d_in, const int* in_sizes, int n_in,
                              void* d_out, int out_size, void* d_ws, size_t ws_size,
                              hipStream_t stream) {
    const float* x    = (const float*)d_in[0];
    const float* wih0 = (const float*)d_in[1];
    const float* whh0 = (const float*)d_in[2];
    const float* bih0 = (const float*)d_in[3];
    const float* bhh0 = (const float*)d_in[4];
    const float* wihL = (const float*)d_in[5];
    const float* whhL = (const float*)d_in[6];
    const float* bihL = (const float*)d_in[7];
    const float* bhhL = (const float*)d_in[8];
    float* out = (float*)d_out;

    gru_all<<<NBLK, 128, 0, stream>>>(x, wih0, whh0, bih0, bhh0,
                                      wihL, whhL, bihL, bhhL, out);
}